// Round 3
// baseline (149.918 us; speedup 1.0000x reference)
//
#include <hip/hip_runtime.h>

typedef __attribute__((ext_vector_type(8))) short short8;
typedef __attribute__((ext_vector_type(4))) float f32x4;

#define IN_DIM 256
#define OUT_DIM 256
#define NB 16                 // padded basis count (13 real + 3 zero)
#define KDIM (IN_DIM * NB)    // 4096
#define TM 128
#define TN 128
#define BK 64                 // 4 i-values per K-step
#define LDA 72                // padded LDS row stride (bf16): balanced banks for frag reads AND row writes
#define KSPLIT 8
#define IPER (IN_DIM / KSPLIT)   // 32 i-values per block
#define STEPS (IPER / 4)         // 8
#define XST 4                    // x-exchange row stride (floats)

__device__ __forceinline__ unsigned short f2bf(float f) {
  union { float f; unsigned int u; } v; v.f = f;
  unsigned int r = v.u + 0x7fffu + ((v.u >> 16) & 1u);  // RNE
  return (unsigned short)(r >> 16);
}

// --- prep: BmT[o][i*16+n] = bf16( sum_e softmax(gating[i,o,:])[e] * coeff[e,n] )
__global__ __launch_bounds__(256) void kan_prep(const float* __restrict__ coeff,
                                                const float* __restrict__ gw,
                                                unsigned short* __restrict__ BmT) {
  __shared__ float csh[104];
  __shared__ unsigned short tile[16][256];   // [o_loc][il*16+n]
  const int t = threadIdx.x;
  if (t < 104) csh[t] = coeff[t];
  __syncthreads();
  const int otile = blockIdx.x, itile = blockIdx.y;
  const int il = t >> 4, ol = t & 15;
  const int i = itile * 16 + il;
  const int o = otile * 16 + ol;
  const float* g = gw + (size_t)(i * OUT_DIM + o) * 8;
  float4 g0 = *(const float4*)g;
  float4 g1 = *(const float4*)(g + 4);
  float ge[8] = {g0.x, g0.y, g0.z, g0.w, g1.x, g1.y, g1.z, g1.w};
  float mx = ge[0];
#pragma unroll
  for (int e = 1; e < 8; ++e) mx = fmaxf(mx, ge[e]);
  float p[8]; float s = 0.f;
#pragma unroll
  for (int e = 0; e < 8; ++e) { p[e] = __expf(ge[e] - mx); s += p[e]; }
  const float inv = 1.0f / s;
  unsigned short row[16];
#pragma unroll
  for (int n = 0; n < 13; ++n) {
    float w = 0.f;
#pragma unroll
    for (int e = 0; e < 8; ++e) w += p[e] * csh[e * 13 + n];
    row[n] = f2bf(w * inv);
  }
  row[13] = 0; row[14] = 0; row[15] = 0;
  int4* dst = (int4*)&tile[ol][il * 16];
  dst[0] = *(const int4*)&row[0];
  dst[1] = *(const int4*)&row[8];
  __syncthreads();
  const int oo = t >> 4, ck = t & 15;
  int4 v0 = *(const int4*)&tile[oo][ck * 16];
  int4 v1 = *(const int4*)&tile[oo][ck * 16 + 8];
  int4* out4 = (int4*)(BmT + (size_t)(otile * 16 + oo) * KDIM + itile * 256 + ck * 16);
  out4[0] = v0;
  out4[1] = v1;
}

// --- fused basis + GEMM: out[m][o] += A[m][k] * BmT[o][k], k = i*16+n
__global__ __launch_bounds__(256, 4) void kan_gemm(const float* __restrict__ x,
                                                   const unsigned short* __restrict__ BmT,
                                                   float* __restrict__ out) {
  __shared__ int4 AshR[(TM * LDA * 2) / 16];   // 18432 B
  __shared__ int4 BshR[(TN * LDA * 2) / 16];   // 18432 B
  __shared__ float Xex[2][TM * XST];           // 4096 B  (total 40960 B -> 4 blocks/CU)
  unsigned short* Ash = (unsigned short*)AshR;
  unsigned short* Bsh = (unsigned short*)BshR;

  const int t = threadIdx.x;
  const int lane = t & 63;
  const int wave = t >> 6;
  const int wm = wave & 1, wn = wave >> 1;       // 2x2 waves, 64x64 each
  const int mb = blockIdx.x * TM;
  const int ob = blockIdx.y * TN;
  const int i0 = blockIdx.z * IPER;

  const int mloc = t & 127;
  const int il0 = t >> 7;                        // covers il0 and il0+2
  const int arow = mloc * LDA;

  // x loader mapping: 4 consecutive lanes cover the step's 4 columns of one row
  const int xrow = t >> 2;                       // 0..63 (plus +64 for second)
  const int xcol = t & 3;
  const float* xb0 = x + (size_t)(mb + xrow) * IN_DIM + i0 + xcol;
  const float* xb1 = xb0 + (size_t)64 * IN_DIM;

  // B loader: 4 rows of 128B per thread-row-group, fully coalesced
  const unsigned short* bsrc[4];
  int bdst[4];
#pragma unroll
  for (int r = 0; r < 4; ++r) {
    int olo = (t >> 3) + 32 * r;
    bsrc[r] = BmT + (size_t)(ob + olo) * KDIM + i0 * NB + (t & 7) * 8;
    bdst[r] = olo * LDA + (t & 7) * 8;
  }

  f32x4 acc[4][4];
#pragma unroll
  for (int a = 0; a < 4; ++a)
#pragma unroll
    for (int b = 0; b < 4; ++b) acc[a][b] = (f32x4){0.f, 0.f, 0.f, 0.f};

  int aoff[4], boff[4];
#pragma unroll
  for (int f = 0; f < 4; ++f) {
    aoff[f] = (wm * 64 + f * 16 + (lane & 15)) * LDA + (lane >> 4) * 8;
    boff[f] = (wn * 64 + f * 16 + (lane & 15)) * LDA + (lane >> 4) * 8;
  }

  // ---- prologue: step-0 x into Xex[0]; step-1 x into regs; step-0 B into regs
  {
    float a0 = xb0[0], a1 = xb1[0];
    Xex[0][xrow * XST + xcol] = a0;
    Xex[0][(xrow + 64) * XST + xcol] = a1;
  }
  float xr1[2];
  xr1[0] = xb0[4];
  xr1[1] = xb1[4];
  int4 breg[4];
#pragma unroll
  for (int r = 0; r < 4; ++r) breg[r] = *(const int4*)(bsrc[r]);

  for (int s = 0; s < STEPS; ++s) {
    __syncthreads();
    // stage B (prefetched regs -> LDS)
#pragma unroll
    for (int r = 0; r < 4; ++r) *(int4*)&Bsh[bdst[r]] = breg[r];
    // stage next step's x (prefetched regs -> other Xex buffer)
    {
      float* xd = (float*)Xex[(s + 1) & 1];
      xd[xrow * XST + xcol] = xr1[0];
      xd[(xrow + 64) * XST + xcol] = xr1[1];
    }
    // prefetch B for s+1
    if (s + 1 < STEPS) {
#pragma unroll
      for (int r = 0; r < 4; ++r) breg[r] = *(const int4*)(bsrc[r] + (s + 1) * BK);
    }
    // prefetch x for s+2 (coalesced-ish: 4 lanes/row)
    {
      int sn = s + 2 < STEPS ? s + 2 : s;        // harmless dummy on tail
      xr1[0] = xb0[sn * 4];
      xr1[1] = xb1[sn * 4];
    }
    // spline A rows from this step's Xex, full-row vector writes
    {
      const float* xs = (const float*)Xex[s & 1];
#pragma unroll
      for (int r = 0; r < 2; ++r) {
        const int il = il0 + 2 * r;
        float xv = xs[mloc * XST + il];
        float xc = fminf(fmaxf(xv, -1.0f), 1.0f - 1e-6f);
        float u = (xc + 1.0f) * 5.0f;            // h = 0.2
        int c = (int)u;
        c = c > 9 ? 9 : (c < 0 ? 0 : c);
        float tt = u - (float)c;
        float omt = 1.0f - tt;
        float t2 = tt * tt, t3 = t2 * tt;
        float b0 = omt * omt * omt * (1.0f / 6.0f);
        float b1 = (3.0f * t3 - 6.0f * t2 + 4.0f) * (1.0f / 6.0f);
        float b2 = (-3.0f * t3 + 3.0f * t2 + 3.0f * tt + 1.0f) * (1.0f / 6.0f);
        float b3 = t3 * (1.0f / 6.0f);
        unsigned h0 = f2bf(b0), h1 = f2bf(b1), h2 = f2bf(b2), h3 = f2bf(b3);
        // pack 16 bf16 slots (4 nonzeros at c..c+3) into 8 dwords, branchless
        const int a = c >> 1;
        const bool odd = (c & 1) != 0;
        unsigned p01 = h0 | (h1 << 16);
        unsigned p23 = h2 | (h3 << 16);
        unsigned A0 = odd ? (h0 << 16) : p01;
        unsigned A1 = odd ? (h1 | (h2 << 16)) : p23;
        unsigned A2 = odd ? h3 : 0u;
        unsigned d[8];
#pragma unroll
        for (int j = 0; j < 8; ++j) {
          unsigned v = (j == a) ? A0 : 0u;
          v = (j == a + 1) ? A1 : v;
          v = (j == a + 2) ? A2 : v;
          d[j] = v;
        }
        *(int4*)&Ash[arow + il * NB] = *(const int4*)&d[0];
        *(int4*)&Ash[arow + il * NB + 8] = *(const int4*)&d[4];
      }
    }
    __syncthreads();
    // MFMA phase: 16 frag reads, 32 MFMAs per wave
#pragma unroll
    for (int kc = 0; kc < 2; ++kc) {
      short8 af[4], bfr[4];
#pragma unroll
      for (int f = 0; f < 4; ++f) af[f] = *(const short8*)&Ash[aoff[f] + kc * 32];
#pragma unroll
      for (int f = 0; f < 4; ++f) bfr[f] = *(const short8*)&Bsh[boff[f] + kc * 32];
#pragma unroll
      for (int mf = 0; mf < 4; ++mf)
#pragma unroll
        for (int nf = 0; nf < 4; ++nf)
          acc[mf][nf] = __builtin_amdgcn_mfma_f32_16x16x32_bf16(af[mf], bfr[nf], acc[mf][nf], 0, 0, 0);
    }
  }

  // epilogue: split-K accumulate
#pragma unroll
  for (int mf = 0; mf < 4; ++mf)
#pragma unroll
    for (int nf = 0; nf < 4; ++nf)
#pragma unroll
      for (int r = 0; r < 4; ++r) {
        int row = mb + wm * 64 + mf * 16 + ((lane >> 4) << 2) + r;
        int col = ob + wn * 64 + nf * 16 + (lane & 15);
        atomicAdd(out + (size_t)row * OUT_DIM + col, acc[mf][nf][r]);
      }
}

extern "C" void kernel_launch(void* const* d_in, const int* in_sizes, int n_in,
                              void* d_out, int out_size, void* d_ws, size_t ws_size,
                              hipStream_t stream) {
  const float* x     = (const float*)d_in[0];   // (4,2048,256) f32
  const float* coeff = (const float*)d_in[1];   // (8,13) f32
  const float* gw    = (const float*)d_in[2];   // (256,256,8) f32
  float* out = (float*)d_out;                   // (4,2048,256) f32
  unsigned short* BmT = (unsigned short*)d_ws;  // 256 x 4096 bf16 = 2 MB

  hipMemsetAsync(d_out, 0, (size_t)out_size * sizeof(float), stream);
  kan_prep<<<dim3(16, 16), dim3(256), 0, stream>>>(coeff, gw, BmT);
  dim3 grid(8192 / TM, OUT_DIM / TN, KSPLIT);
  kan_gemm<<<grid, dim3(256), 0, stream>>>(x, BmT, out);
}

// Round 4
// 127.351 us; speedup vs baseline: 1.1772x; 1.1772x over previous
//
#include <hip/hip_runtime.h>

typedef __attribute__((ext_vector_type(8))) short short8;
typedef __attribute__((ext_vector_type(4))) float f32x4;

#define IN_DIM 256
#define OUT_DIM 256
#define NB 16                 // padded basis count (13 real + 3 zero)
#define KDIM (IN_DIM * NB)    // 4096
#define TM 128
#define TN 128
#define BK 64                 // 4 i-values per K-step
#define LDA 72                // padded LDS row stride (bf16): balanced banks for frag reads AND row writes
#define KSPLIT 2
#define IPER (IN_DIM / KSPLIT)   // 128 i-values per block
#define STEPS (IPER / 4)         // 32
#define XPITCH 129               // Xsh row pitch in f32 (+1 pad -> conflict-free scalar reads)
#define XBYTES (TM * XPITCH * 4)          // 66048
#define ABYTES (TM * LDA * 2)             // 18432 per buffer
#define LDS_TOTAL (XBYTES + 4 * ABYTES)   // 139776 (< 160 KiB)

__device__ __forceinline__ unsigned short f2bf(float f) {
  union { float f; unsigned int u; } v; v.f = f;
  unsigned int r = v.u + 0x7fffu + ((v.u >> 16) & 1u);  // RNE
  return (unsigned short)(r >> 16);
}

// branchless cubic B-spline row: 16 bf16 slots, 4 nonzeros at c..c+3
__device__ __forceinline__ void spline_row(float xv, unsigned short* rowp) {
  float xc = fminf(fmaxf(xv, -1.0f), 1.0f - 1e-6f);
  float u = (xc + 1.0f) * 5.0f;            // h = 0.2
  int c = (int)u;
  c = c > 9 ? 9 : (c < 0 ? 0 : c);
  float tt = u - (float)c;
  float omt = 1.0f - tt;
  float t2 = tt * tt, t3 = t2 * tt;
  float b0 = omt * omt * omt * (1.0f / 6.0f);
  float b1 = (3.0f * t3 - 6.0f * t2 + 4.0f) * (1.0f / 6.0f);
  float b2 = (-3.0f * t3 + 3.0f * t2 + 3.0f * tt + 1.0f) * (1.0f / 6.0f);
  float b3 = t3 * (1.0f / 6.0f);
  unsigned h0 = f2bf(b0), h1 = f2bf(b1), h2 = f2bf(b2), h3 = f2bf(b3);
  const int a = c >> 1;
  const bool odd = (c & 1) != 0;
  unsigned p01 = h0 | (h1 << 16);
  unsigned p23 = h2 | (h3 << 16);
  unsigned A0 = odd ? (h0 << 16) : p01;
  unsigned A1 = odd ? (h1 | (h2 << 16)) : p23;
  unsigned A2 = odd ? h3 : 0u;
  unsigned d[8];
#pragma unroll
  for (int j = 0; j < 8; ++j) {
    unsigned v = (j == a) ? A0 : 0u;
    v = (j == a + 1) ? A1 : v;
    v = (j == a + 2) ? A2 : v;
    d[j] = v;
  }
  *(int4*)&rowp[0] = *(const int4*)&d[0];
  *(int4*)&rowp[8] = *(const int4*)&d[4];
}

// --- prep: BmT[o][i*16+n] = bf16( sum_e softmax(gating[i,o,:])[e] * coeff[e,n] ); also zeroes out
__global__ __launch_bounds__(256) void kan_prep(const float* __restrict__ coeff,
                                                const float* __restrict__ gw,
                                                unsigned short* __restrict__ BmT,
                                                float* __restrict__ out) {
  __shared__ float csh[104];
  __shared__ unsigned short tile[16][256];   // [o_loc][il*16+n]
  const int t = threadIdx.x;
  // zero the output (replaces a separate memset node); coalesced f4 stores
  {
    const int bid = blockIdx.y * 16 + blockIdx.x;
    float4 z; z.x = z.y = z.z = z.w = 0.f;
    float4* ob = (float4*)out;
#pragma unroll
    for (int j = 0; j < 8; ++j) ob[(size_t)bid * 2048 + j * 256 + t] = z;
  }
  if (t < 104) csh[t] = coeff[t];
  __syncthreads();
  const int otile = blockIdx.x, itile = blockIdx.y;
  const int il = t >> 4, ol = t & 15;
  const int i = itile * 16 + il;
  const int o = otile * 16 + ol;
  const float* g = gw + (size_t)(i * OUT_DIM + o) * 8;
  float4 g0 = *(const float4*)g;
  float4 g1 = *(const float4*)(g + 4);
  float ge[8] = {g0.x, g0.y, g0.z, g0.w, g1.x, g1.y, g1.z, g1.w};
  float mx = ge[0];
#pragma unroll
  for (int e = 1; e < 8; ++e) mx = fmaxf(mx, ge[e]);
  float p[8]; float s = 0.f;
#pragma unroll
  for (int e = 0; e < 8; ++e) { p[e] = __expf(ge[e] - mx); s += p[e]; }
  const float inv = 1.0f / s;
  unsigned short row[16];
#pragma unroll
  for (int n = 0; n < 13; ++n) {
    float w = 0.f;
#pragma unroll
    for (int e = 0; e < 8; ++e) w += p[e] * csh[e * 13 + n];
    row[n] = f2bf(w * inv);
  }
  row[13] = 0; row[14] = 0; row[15] = 0;
  int4* dst = (int4*)&tile[ol][il * 16];
  dst[0] = *(const int4*)&row[0];
  dst[1] = *(const int4*)&row[8];
  __syncthreads();
  const int oo = t >> 4, ck = t & 15;
  int4 v0 = *(const int4*)&tile[oo][ck * 16];
  int4 v1 = *(const int4*)&tile[oo][ck * 16 + 8];
  int4* out4 = (int4*)(BmT + (size_t)(otile * 16 + oo) * KDIM + itile * 256 + ck * 16);
  out4[0] = v0;
  out4[1] = v1;
}

// --- fused basis + GEMM: out[m][o] += A[m][k] * BmT[o][k], k = i*16+n
// One barrier/step, double-buffered A/B tiles, x-tile resident in LDS.
__global__ __launch_bounds__(256, 1) void kan_gemm(const float* __restrict__ x,
                                                   const unsigned short* __restrict__ BmT,
                                                   float* __restrict__ out) {
  extern __shared__ char lds_raw[];
  float* Xsh = (float*)lds_raw;                                  // [TM][XPITCH]
  unsigned short* AshB = (unsigned short*)(lds_raw + XBYTES);    // [2][TM*LDA]
  unsigned short* BshB = AshB + 2 * TM * LDA;                    // [2][TN*LDA]

  const int t = threadIdx.x;
  const int lane = t & 63;
  const int wave = t >> 6;
  const int wm = wave & 1, wn = wave >> 1;       // 2x2 waves, 64x64 each
  const int mb = blockIdx.x * TM;
  const int ob = blockIdx.y * TN;
  const int i0 = blockIdx.z * IPER;

  const int mloc = t & 127;
  const int il0 = t >> 7;                        // covers il0 and il0+2

  // ---- prologue: coalesced x-tile load -> Xsh (once per block; no x in the loop)
  {
    const int xr = t >> 5;     // 0..7
    const int xc = t & 31;     // 0..31  (32 lanes x 16B = one 512B row segment)
#pragma unroll
    for (int p = 0; p < 16; ++p) {
      const int r = xr + 8 * p;
      float4 v = *(const float4*)(x + (size_t)(mb + r) * IN_DIM + i0 + xc * 4);
      float* d = Xsh + r * XPITCH + xc * 4;
      d[0] = v.x; d[1] = v.y; d[2] = v.z; d[3] = v.w;
    }
  }

  // B loader: 4 rows of 128B per thread, coalesced
  const unsigned short* bsrc[4];
  int bdst[4];
#pragma unroll
  for (int r = 0; r < 4; ++r) {
    int olo = (t >> 3) + 32 * r;
    bsrc[r] = BmT + (size_t)(ob + olo) * KDIM + i0 * NB + (t & 7) * 8;
    bdst[r] = olo * LDA + (t & 7) * 8;
  }

  int4 breg[4];
#pragma unroll
  for (int r = 0; r < 4; ++r) breg[r] = *(const int4*)(bsrc[r]);

  f32x4 acc[4][4];
#pragma unroll
  for (int a = 0; a < 4; ++a)
#pragma unroll
    for (int b = 0; b < 4; ++b) acc[a][b] = (f32x4){0.f, 0.f, 0.f, 0.f};

  int aoff[4], boff[4];
#pragma unroll
  for (int f = 0; f < 4; ++f) {
    aoff[f] = (wm * 64 + f * 16 + (lane & 15)) * LDA + (lane >> 4) * 8;
    boff[f] = (wn * 64 + f * 16 + (lane & 15)) * LDA + (lane >> 4) * 8;
  }

  __syncthreads();   // Xsh visible to all waves

  // stage step 0 into buffer 0
  {
#pragma unroll
    for (int r = 0; r < 4; ++r) *(int4*)&BshB[bdst[r]] = breg[r];
#pragma unroll
    for (int rr = 0; rr < 2; ++rr) {
      const int il = il0 + 2 * rr;
      spline_row(Xsh[mloc * XPITCH + il], AshB + mloc * LDA + il * NB);
    }
  }

  for (int s = 0; s < STEPS; ++s) {
    __syncthreads();                    // buf[s&1] complete for all waves
    const int cur = s & 1;
    const bool more = (s + 1 < STEPS);
    // issue next step's B loads NOW: consumed at end of this step, so the
    // wait is covered by the whole MFMA phase (no zero-cover barrier drain)
    if (more) {
#pragma unroll
      for (int r = 0; r < 4; ++r) breg[r] = *(const int4*)(bsrc[r] + (s + 1) * BK);
    }
    // MFMA phase on buf[cur]
    const unsigned short* Ac = AshB + cur * (TM * LDA);
    const unsigned short* Bc = BshB + cur * (TN * LDA);
#pragma unroll
    for (int kc = 0; kc < 2; ++kc) {
      short8 af[4], bfr[4];
#pragma unroll
      for (int f = 0; f < 4; ++f) af[f] = *(const short8*)&Ac[aoff[f] + kc * 32];
#pragma unroll
      for (int f = 0; f < 4; ++f) bfr[f] = *(const short8*)&Bc[boff[f] + kc * 32];
#pragma unroll
      for (int mf = 0; mf < 4; ++mf)
#pragma unroll
        for (int nf = 0; nf < 4; ++nf)
          acc[mf][nf] = __builtin_amdgcn_mfma_f32_16x16x32_bf16(af[mf], bfr[nf], acc[mf][nf], 0, 0, 0);
    }
    // stage step s+1 into buf[1-cur] (other waves may still read buf[cur]: safe)
    if (more) {
      unsigned short* An = AshB + (1 - cur) * (TM * LDA);
      unsigned short* Bn = BshB + (1 - cur) * (TN * LDA);
#pragma unroll
      for (int r = 0; r < 4; ++r) *(int4*)&Bn[bdst[r]] = breg[r];
#pragma unroll
      for (int rr = 0; rr < 2; ++rr) {
        const int il = il0 + 2 * rr;
        spline_row(Xsh[mloc * XPITCH + (s + 1) * 4 + il], An + mloc * LDA + il * NB);
      }
    }
  }

  // epilogue: split-K accumulate
#pragma unroll
  for (int mf = 0; mf < 4; ++mf)
#pragma unroll
    for (int nf = 0; nf < 4; ++nf)
#pragma unroll
      for (int r = 0; r < 4; ++r) {
        int row = mb + wm * 64 + mf * 16 + ((lane >> 4) << 2) + r;
        int col = ob + wn * 64 + nf * 16 + (lane & 15);
        atomicAdd(out + (size_t)row * OUT_DIM + col, acc[mf][nf][r]);
      }
}

extern "C" void kernel_launch(void* const* d_in, const int* in_sizes, int n_in,
                              void* d_out, int out_size, void* d_ws, size_t ws_size,
                              hipStream_t stream) {
  const float* x     = (const float*)d_in[0];   // (4,2048,256) f32
  const float* coeff = (const float*)d_in[1];   // (8,13) f32
  const float* gw    = (const float*)d_in[2];   // (256,256,8) f32
  float* out = (float*)d_out;                   // (4,2048,256) f32
  unsigned short* BmT = (unsigned short*)d_ws;  // 256 x 4096 bf16 = 2 MB

  hipFuncSetAttribute((const void*)kan_gemm,
                      hipFuncAttributeMaxDynamicSharedMemorySize, LDS_TOTAL);
  kan_prep<<<dim3(16, 16), dim3(256), 0, stream>>>(coeff, gw, BmT, out);
  dim3 grid(8192 / TM, OUT_DIM / TN, KSPLIT);
  kan_gemm<<<grid, dim3(256), LDS_TOTAL, stream>>>(x, BmT, out);
}

// Round 5
// 112.414 us; speedup vs baseline: 1.3336x; 1.1329x over previous
//
#include <hip/hip_runtime.h>

typedef __attribute__((ext_vector_type(8))) short short8;
typedef __attribute__((ext_vector_type(4))) float f32x4;

#define IN_DIM 256
#define OUT_DIM 256
#define NB 16                 // padded basis count (13 real + 3 zero)
#define KDIM (IN_DIM * NB)    // 4096
#define TM 128
#define TN 128
#define BK 64                 // 4 i-values per K-step
#define LDA 72                // padded LDS row stride (bf16)
#define KSPLIT 4
#define IPER (IN_DIM / KSPLIT)   // 64 i-values per block
#define STEPS (IPER / 4)         // 16

__device__ __forceinline__ unsigned short f2bf(float f) {
  union { float f; unsigned int u; } v; v.f = f;
  unsigned int r = v.u + 0x7fffu + ((v.u >> 16) & 1u);  // RNE
  return (unsigned short)(r >> 16);
}

// branchless cubic B-spline row: 16 bf16 slots, 4 nonzeros at c..c+3
__device__ __forceinline__ void spline_row(float xv, unsigned short* rowp) {
  float xc = fminf(fmaxf(xv, -1.0f), 1.0f - 1e-6f);
  float u = (xc + 1.0f) * 5.0f;            // h = 0.2
  int c = (int)u;
  c = c > 9 ? 9 : (c < 0 ? 0 : c);
  float tt = u - (float)c;
  float omt = 1.0f - tt;
  float t2 = tt * tt, t3 = t2 * tt;
  float b0 = omt * omt * omt * (1.0f / 6.0f);
  float b1 = (3.0f * t3 - 6.0f * t2 + 4.0f) * (1.0f / 6.0f);
  float b2 = (-3.0f * t3 + 3.0f * t2 + 3.0f * tt + 1.0f) * (1.0f / 6.0f);
  float b3 = t3 * (1.0f / 6.0f);
  unsigned h0 = f2bf(b0), h1 = f2bf(b1), h2 = f2bf(b2), h3 = f2bf(b3);
  const int a = c >> 1;
  const bool odd = (c & 1) != 0;
  unsigned p01 = h0 | (h1 << 16);
  unsigned p23 = h2 | (h3 << 16);
  unsigned A0 = odd ? (h0 << 16) : p01;
  unsigned A1 = odd ? (h1 | (h2 << 16)) : p23;
  unsigned A2 = odd ? h3 : 0u;
  unsigned d[8];
#pragma unroll
  for (int j = 0; j < 8; ++j) {
    unsigned v = (j == a) ? A0 : 0u;
    v = (j == a + 1) ? A1 : v;
    v = (j == a + 2) ? A2 : v;
    d[j] = v;
  }
  *(int4*)&rowp[0] = *(const int4*)&d[0];
  *(int4*)&rowp[8] = *(const int4*)&d[4];
}

// --- prep: BmT[o][i*16+n] = bf16( sum_e softmax(gating[i,o,:])[e] * coeff[e,n] ); also zeroes out
__global__ __launch_bounds__(256) void kan_prep(const float* __restrict__ coeff,
                                                const float* __restrict__ gw,
                                                unsigned short* __restrict__ BmT,
                                                float* __restrict__ out) {
  __shared__ float csh[104];
  __shared__ unsigned short tile[16][256];   // [o_loc][il*16+n]
  const int t = threadIdx.x;
  // zero the output (atomic split-K needs zeros); coalesced f4 stores
  {
    const int bid = blockIdx.y * 16 + blockIdx.x;
    float4 z; z.x = z.y = z.z = z.w = 0.f;
    float4* ob = (float4*)out;
#pragma unroll
    for (int j = 0; j < 8; ++j) ob[(size_t)bid * 2048 + j * 256 + t] = z;
  }
  if (t < 104) csh[t] = coeff[t];
  __syncthreads();
  const int otile = blockIdx.x, itile = blockIdx.y;
  const int il = t >> 4, ol = t & 15;
  const int i = itile * 16 + il;
  const int o = otile * 16 + ol;
  const float* g = gw + (size_t)(i * OUT_DIM + o) * 8;
  float4 g0 = *(const float4*)g;
  float4 g1 = *(const float4*)(g + 4);
  float ge[8] = {g0.x, g0.y, g0.z, g0.w, g1.x, g1.y, g1.z, g1.w};
  float mx = ge[0];
#pragma unroll
  for (int e = 1; e < 8; ++e) mx = fmaxf(mx, ge[e]);
  float p[8]; float s = 0.f;
#pragma unroll
  for (int e = 0; e < 8; ++e) { p[e] = __expf(ge[e] - mx); s += p[e]; }
  const float inv = 1.0f / s;
  unsigned short row[16];
#pragma unroll
  for (int n = 0; n < 13; ++n) {
    float w = 0.f;
#pragma unroll
    for (int e = 0; e < 8; ++e) w += p[e] * csh[e * 13 + n];
    row[n] = f2bf(w * inv);
  }
  row[13] = 0; row[14] = 0; row[15] = 0;
  int4* dst = (int4*)&tile[ol][il * 16];
  dst[0] = *(const int4*)&row[0];
  dst[1] = *(const int4*)&row[8];
  __syncthreads();
  const int oo = t >> 4, ck = t & 15;
  int4 v0 = *(const int4*)&tile[oo][ck * 16];
  int4 v1 = *(const int4*)&tile[oo][ck * 16 + 8];
  int4* out4 = (int4*)(BmT + (size_t)(otile * 16 + oo) * KDIM + itile * 256 + ck * 16);
  out4[0] = v0;
  out4[1] = v1;
}

// --- fused basis + GEMM: out[m][o] += A[m][k] * BmT[o][k], k = i*16+n
// One barrier/step, double-buffered A/B tiles, 73728 B LDS -> 2 blocks/CU.
// All global loads are issued and consumed within one barrier interval
// (no cross-barrier outstanding loads -> no vmcnt(0) drain stall).
__global__ __launch_bounds__(256, 2) void kan_gemm(const float* __restrict__ x,
                                                   const unsigned short* __restrict__ BmT,
                                                   float* __restrict__ out) {
  __shared__ unsigned short AshB[2][TM * LDA];   // 36864 B
  __shared__ unsigned short BshB[2][TN * LDA];   // 36864 B

  const int t = threadIdx.x;
  const int lane = t & 63;
  const int wave = t >> 6;
  const int wm = wave & 1, wn = wave >> 1;       // 2x2 waves, 64x64 each
  const int mb = blockIdx.x * TM;
  const int ob = blockIdx.y * TN;
  const int i0 = blockIdx.z * IPER;

  // A-stager mapping: thread = (row r, col-pair ph); covers ils {2ph, 2ph+1}
  const int r = t & 127;
  const int ph = t >> 7;
  const float* xrow = x + (size_t)(mb + r) * IN_DIM + i0 + 2 * ph;
  const int adst = r * LDA + 2 * ph * NB;        // elem offset of il=2ph chunk

  // B loader: 4 rows of 128B per thread, coalesced
  const unsigned short* bsrc[4];
  int bdst[4];
#pragma unroll
  for (int q = 0; q < 4; ++q) {
    int olo = (t >> 3) + 32 * q;
    bsrc[q] = BmT + (size_t)(ob + olo) * KDIM + i0 * NB + (t & 7) * 8;
    bdst[q] = olo * LDA + (t & 7) * 8;
  }

  f32x4 acc[4][4];
#pragma unroll
  for (int a = 0; a < 4; ++a)
#pragma unroll
    for (int b = 0; b < 4; ++b) acc[a][b] = (f32x4){0.f, 0.f, 0.f, 0.f};

  int aoff[4], boff[4];
#pragma unroll
  for (int f = 0; f < 4; ++f) {
    aoff[f] = (wm * 64 + f * 16 + (lane & 15)) * LDA + (lane >> 4) * 8;
    boff[f] = (wn * 64 + f * 16 + (lane & 15)) * LDA + (lane >> 4) * 8;
  }

  // ---- prologue: stage step 0 into buffer 0
  {
    float2 x0 = *(const float2*)xrow;
    int4 breg[4];
#pragma unroll
    for (int q = 0; q < 4; ++q) breg[q] = *(const int4*)(bsrc[q]);
#pragma unroll
    for (int q = 0; q < 4; ++q) *(int4*)&BshB[0][bdst[q]] = breg[q];
    spline_row(x0.x, &AshB[0][adst]);
    spline_row(x0.y, &AshB[0][adst + NB]);
  }

  for (int s = 0; s < STEPS; ++s) {
    __syncthreads();                    // buf[s&1] complete for all waves
    const int cur = s & 1;
    const bool more = (s + 1 < STEPS);
    // issue next step's globals NOW; consumed at end of this step
    int4 breg[4];
    float2 xn;
    if (more) {
#pragma unroll
      for (int q = 0; q < 4; ++q) breg[q] = *(const int4*)(bsrc[q] + (s + 1) * BK);
      xn = *(const float2*)(xrow + (s + 1) * 4);
    }
    // MFMA phase on buf[cur]
    const unsigned short* Ac = AshB[cur];
    const unsigned short* Bc = BshB[cur];
#pragma unroll
    for (int kc = 0; kc < 2; ++kc) {
      short8 af[4], bfr[4];
#pragma unroll
      for (int f = 0; f < 4; ++f) af[f] = *(const short8*)&Ac[aoff[f] + kc * 32];
#pragma unroll
      for (int f = 0; f < 4; ++f) bfr[f] = *(const short8*)&Bc[boff[f] + kc * 32];
#pragma unroll
      for (int mf = 0; mf < 4; ++mf)
#pragma unroll
        for (int nf = 0; nf < 4; ++nf)
          acc[mf][nf] = __builtin_amdgcn_mfma_f32_16x16x32_bf16(af[mf], bfr[nf], acc[mf][nf], 0, 0, 0);
    }
    // stage step s+1 into buf[1-cur]
    if (more) {
      unsigned short* An = AshB[1 - cur];
      unsigned short* Bn = BshB[1 - cur];
#pragma unroll
      for (int q = 0; q < 4; ++q) *(int4*)&Bn[bdst[q]] = breg[q];
      spline_row(xn.x, An + adst);
      spline_row(xn.y, An + adst + NB);
    }
  }

  // epilogue: split-K accumulate
#pragma unroll
  for (int mf = 0; mf < 4; ++mf)
#pragma unroll
    for (int nf = 0; nf < 4; ++nf)
#pragma unroll
      for (int q = 0; q < 4; ++q) {
        int row = mb + wm * 64 + mf * 16 + ((lane >> 4) << 2) + q;
        int col = ob + wn * 64 + nf * 16 + (lane & 15);
        atomicAdd(out + (size_t)row * OUT_DIM + col, acc[mf][nf][q]);
      }
}

extern "C" void kernel_launch(void* const* d_in, const int* in_sizes, int n_in,
                              void* d_out, int out_size, void* d_ws, size_t ws_size,
                              hipStream_t stream) {
  const float* x     = (const float*)d_in[0];   // (4,2048,256) f32
  const float* coeff = (const float*)d_in[1];   // (8,13) f32
  const float* gw    = (const float*)d_in[2];   // (256,256,8) f32
  float* out = (float*)d_out;                   // (4,2048,256) f32
  unsigned short* BmT = (unsigned short*)d_ws;  // 256 x 4096 bf16 = 2 MB

  kan_prep<<<dim3(16, 16), dim3(256), 0, stream>>>(coeff, gw, BmT, out);
  dim3 grid(8192 / TM, OUT_DIM / TN, KSPLIT);
  kan_gemm<<<grid, dim3(256), 0, stream>>>(x, BmT, out);
}